// Round 5
// baseline (273.398 us; speedup 1.0000x reference)
//
#include <hip/hip_runtime.h>

// Inputs (setup_inputs order):
//  0: coords [100000*3] f32; 1-6: pair i/j/coul/a12/b6/b10 [8M];
//  7-12: pair14 i/j/coul/a12/b6/b10 [500K]
// Output: [4] f32 = [e_coul, e_lj, e_coul14, e_lj14]
//
// R4 diagnosis: latency/MLP-bound gathers (HBM 15%, VALU 14%, no pipe
// saturated). Fix: 8 pairs/lane/iter, issue all 16 coord gathers before
// consuming (2x outstanding loads per wave). Streams stay nontemporal.

#define BLOCK 256
#define GRID  2048

typedef int   intx4   __attribute__((ext_vector_type(4)));
typedef float floatx4 __attribute__((ext_vector_type(4)));

__global__ void pack_coords_kernel(const float* __restrict__ coords,
                                   float4* __restrict__ packed, int natom) {
    int i = blockIdx.x * blockDim.x + threadIdx.x;
    if (i < natom) {
        packed[i] = make_float4(coords[3 * i + 0], coords[3 * i + 1],
                                coords[3 * i + 2], 0.0f);
    }
}

__device__ __forceinline__ void pair_math(float4 ci, float4 cj, float coul,
                                          float a12, float b6, float b10,
                                          double& ec, double& ev) {
    float dx = ci.x - cj.x;
    float dy = ci.y - cj.y;
    float dz = ci.z - cj.z;
    float r2 = dx * dx + dy * dy + dz * dz;
    float inv_r2 = 1.0f / r2;
    float inv_r  = sqrtf(inv_r2);
    float inv_r6 = inv_r2 * inv_r2 * inv_r2;
    ec += (double)(coul * inv_r);
    ev += (double)(a12 * inv_r6 * inv_r6 - b6 * inv_r6
                 - b10 * inv_r6 * inv_r2 * inv_r2);
}

__device__ __forceinline__ void pair_term_packed(const float4* __restrict__ packed,
                                                 int i, int j, float coul, float a12,
                                                 float b6, float b10,
                                                 double& ec, double& ev) {
    pair_math(packed[i], packed[j], coul, a12, b6, b10, ec, ev);
}

__device__ __forceinline__ void pair_term_direct(const float* __restrict__ coords,
                                                 int i, int j, float coul, float a12,
                                                 float b6, float b10,
                                                 double& ec, double& ev) {
    int ia = i * 3, ja = j * 3;
    float4 ci = make_float4(coords[ia], coords[ia + 1], coords[ia + 2], 0.f);
    float4 cj = make_float4(coords[ja], coords[ja + 1], coords[ja + 2], 0.f);
    pair_math(ci, cj, coul, a12, b6, b10, ec, ev);
}

__device__ __forceinline__ void scan_list(const float* __restrict__ coords,
                                          const float4* __restrict__ packed,
                                          const int* __restrict__ ii,
                                          const int* __restrict__ jj,
                                          const float* __restrict__ coul,
                                          const float* __restrict__ a12,
                                          const float* __restrict__ b6,
                                          const float* __restrict__ b10,
                                          int n, int tid, int nthreads,
                                          double& ec, double& ev) {
    if (packed) {
        int n8 = n >> 3;  // chunks of 8 pairs
        for (int c = tid; c < n8; c += nthreads) {
            int base = c * 2;
            intx4   i4a = __builtin_nontemporal_load(((const intx4*)ii) + base);
            intx4   i4b = __builtin_nontemporal_load(((const intx4*)ii) + base + 1);
            intx4   j4a = __builtin_nontemporal_load(((const intx4*)jj) + base);
            intx4   j4b = __builtin_nontemporal_load(((const intx4*)jj) + base + 1);

            // Issue all 16 gathers before consuming any (max MLP).
            float4 CI[8], CJ[8];
            CI[0] = packed[i4a.x]; CI[1] = packed[i4a.y];
            CI[2] = packed[i4a.z]; CI[3] = packed[i4a.w];
            CI[4] = packed[i4b.x]; CI[5] = packed[i4b.y];
            CI[6] = packed[i4b.z]; CI[7] = packed[i4b.w];
            CJ[0] = packed[j4a.x]; CJ[1] = packed[j4a.y];
            CJ[2] = packed[j4a.z]; CJ[3] = packed[j4a.w];
            CJ[4] = packed[j4b.x]; CJ[5] = packed[j4b.y];
            CJ[6] = packed[j4b.z]; CJ[7] = packed[j4b.w];

            floatx4 c4a = __builtin_nontemporal_load(((const floatx4*)coul) + base);
            floatx4 c4b = __builtin_nontemporal_load(((const floatx4*)coul) + base + 1);
            floatx4 a4a = __builtin_nontemporal_load(((const floatx4*)a12) + base);
            floatx4 a4b = __builtin_nontemporal_load(((const floatx4*)a12) + base + 1);
            floatx4 b4a = __builtin_nontemporal_load(((const floatx4*)b6) + base);
            floatx4 b4b = __builtin_nontemporal_load(((const floatx4*)b6) + base + 1);
            floatx4 h4a = __builtin_nontemporal_load(((const floatx4*)b10) + base);
            floatx4 h4b = __builtin_nontemporal_load(((const floatx4*)b10) + base + 1);

            pair_math(CI[0], CJ[0], c4a.x, a4a.x, b4a.x, h4a.x, ec, ev);
            pair_math(CI[1], CJ[1], c4a.y, a4a.y, b4a.y, h4a.y, ec, ev);
            pair_math(CI[2], CJ[2], c4a.z, a4a.z, b4a.z, h4a.z, ec, ev);
            pair_math(CI[3], CJ[3], c4a.w, a4a.w, b4a.w, h4a.w, ec, ev);
            pair_math(CI[4], CJ[4], c4b.x, a4b.x, b4b.x, h4b.x, ec, ev);
            pair_math(CI[5], CJ[5], c4b.y, a4b.y, b4b.y, h4b.y, ec, ev);
            pair_math(CI[6], CJ[6], c4b.z, a4b.z, b4b.z, h4b.z, ec, ev);
            pair_math(CI[7], CJ[7], c4b.w, a4b.w, b4b.w, h4b.w, ec, ev);
        }
        for (int p = (n8 << 3) + tid; p < n; p += nthreads) {
            pair_term_packed(packed, ii[p], jj[p], coul[p], a12[p], b6[p], b10[p], ec, ev);
        }
    } else {
        int n4 = n >> 2;
        for (int c = tid; c < n4; c += nthreads) {
            intx4   i4 = ((const intx4*)ii)[c];
            intx4   j4 = ((const intx4*)jj)[c];
            floatx4 c4 = ((const floatx4*)coul)[c];
            floatx4 a4 = ((const floatx4*)a12)[c];
            floatx4 b4 = ((const floatx4*)b6)[c];
            floatx4 h4 = ((const floatx4*)b10)[c];
            pair_term_direct(coords, i4.x, j4.x, c4.x, a4.x, b4.x, h4.x, ec, ev);
            pair_term_direct(coords, i4.y, j4.y, c4.y, a4.y, b4.y, h4.y, ec, ev);
            pair_term_direct(coords, i4.z, j4.z, c4.z, a4.z, b4.z, h4.z, ec, ev);
            pair_term_direct(coords, i4.w, j4.w, c4.w, a4.w, b4.w, h4.w, ec, ev);
        }
        for (int p = (n4 << 2) + tid; p < n; p += nthreads) {
            pair_term_direct(coords, ii[p], jj[p], coul[p], a12[p], b6[p], b10[p], ec, ev);
        }
    }
}

__global__ __launch_bounds__(BLOCK) void fused_pair_kernel(
        const float* __restrict__ coords, const float4* __restrict__ packed,
        const int* __restrict__ p_i, const int* __restrict__ p_j,
        const float* __restrict__ p_coul, const float* __restrict__ p_a12,
        const float* __restrict__ p_b6, const float* __restrict__ p_b10, int n_pair,
        const int* __restrict__ q_i, const int* __restrict__ q_j,
        const float* __restrict__ q_coul, const float* __restrict__ q_a12,
        const float* __restrict__ q_b6, const float* __restrict__ q_b10, int n_pair14,
        double* __restrict__ partials) {
    double ec = 0.0, ev = 0.0, ec14 = 0.0, ev14 = 0.0;
    int tid = blockIdx.x * blockDim.x + threadIdx.x;
    int nthreads = gridDim.x * blockDim.x;

    scan_list(coords, packed, p_i, p_j, p_coul, p_a12, p_b6, p_b10, n_pair,
              tid, nthreads, ec, ev);
    scan_list(coords, packed, q_i, q_j, q_coul, q_a12, q_b6, q_b10, n_pair14,
              tid, nthreads, ec14, ev14);

    for (int off = 32; off > 0; off >>= 1) {
        ec   += __shfl_down(ec,   off, 64);
        ev   += __shfl_down(ev,   off, 64);
        ec14 += __shfl_down(ec14, off, 64);
        ev14 += __shfl_down(ev14, off, 64);
    }

    __shared__ double s[BLOCK / 64][4];
    int lane = threadIdx.x & 63;
    int wid  = threadIdx.x >> 6;
    if (lane == 0) { s[wid][0] = ec; s[wid][1] = ev; s[wid][2] = ec14; s[wid][3] = ev14; }
    __syncthreads();

    if (threadIdx.x == 0) {
        double t0 = 0, t1 = 0, t2 = 0, t3 = 0;
        for (int w = 0; w < BLOCK / 64; ++w) {
            t0 += s[w][0]; t1 += s[w][1]; t2 += s[w][2]; t3 += s[w][3];
        }
        double* row = partials + (size_t)blockIdx.x * 4;
        row[0] = t0; row[1] = t1; row[2] = t2; row[3] = t3;
    }
}

__global__ __launch_bounds__(BLOCK) void finalize_kernel(
        const double* __restrict__ partials, int nrows,
        float* __restrict__ out) {
    double acc0 = 0, acc1 = 0, acc2 = 0, acc3 = 0;
    for (int r = threadIdx.x; r < nrows; r += blockDim.x) {
        const double* row = partials + (size_t)r * 4;
        acc0 += row[0]; acc1 += row[1]; acc2 += row[2]; acc3 += row[3];
    }
    for (int off = 32; off > 0; off >>= 1) {
        acc0 += __shfl_down(acc0, off, 64);
        acc1 += __shfl_down(acc1, off, 64);
        acc2 += __shfl_down(acc2, off, 64);
        acc3 += __shfl_down(acc3, off, 64);
    }
    __shared__ double s[BLOCK / 64][4];
    int lane = threadIdx.x & 63;
    int wid  = threadIdx.x >> 6;
    if (lane == 0) { s[wid][0] = acc0; s[wid][1] = acc1; s[wid][2] = acc2; s[wid][3] = acc3; }
    __syncthreads();
    if (threadIdx.x == 0) {
        double t0 = 0, t1 = 0, t2 = 0, t3 = 0;
        for (int w = 0; w < BLOCK / 64; ++w) {
            t0 += s[w][0]; t1 += s[w][1]; t2 += s[w][2]; t3 += s[w][3];
        }
        out[0] = (float)t0; out[1] = (float)t1;
        out[2] = (float)t2; out[3] = (float)t3;
    }
}

extern "C" void kernel_launch(void* const* d_in, const int* in_sizes, int n_in,
                              void* d_out, int out_size, void* d_ws, size_t ws_size,
                              hipStream_t stream) {
    const float* coords = (const float*)d_in[0];
    int natom = in_sizes[0] / 3;

    const int*   p_i    = (const int*)d_in[1];
    const int*   p_j    = (const int*)d_in[2];
    const float* p_coul = (const float*)d_in[3];
    const float* p_a12  = (const float*)d_in[4];
    const float* p_b6   = (const float*)d_in[5];
    const float* p_b10  = (const float*)d_in[6];
    int n_pair = in_sizes[1];

    const int*   q_i    = (const int*)d_in[7];
    const int*   q_j    = (const int*)d_in[8];
    const float* q_coul = (const float*)d_in[9];
    const float* q_a12  = (const float*)d_in[10];
    const float* q_b6   = (const float*)d_in[11];
    const float* q_b10  = (const float*)d_in[12];
    int n_pair14 = in_sizes[7];

    float* out = (float*)d_out;

    // d_ws layout: [packed coords: natom*16B] [partials: GRID*32B]
    size_t packed_bytes = (size_t)natom * sizeof(float4);
    size_t need = packed_bytes + (size_t)GRID * 4 * sizeof(double);

    float4* packed   = nullptr;
    double* partials = (double*)d_ws;
    int blocks = GRID;

    if (ws_size >= need) {
        packed   = (float4*)d_ws;
        partials = (double*)((char*)d_ws + packed_bytes);
        hipLaunchKernelGGL(pack_coords_kernel,
                           dim3((natom + BLOCK - 1) / BLOCK), dim3(BLOCK), 0, stream,
                           coords, packed, natom);
    } else {
        size_t max_blocks = ws_size / (4 * sizeof(double));
        if ((size_t)blocks > max_blocks) blocks = (int)max_blocks;
        if (blocks < 1) blocks = 1;
    }

    hipLaunchKernelGGL(fused_pair_kernel, dim3(blocks), dim3(BLOCK), 0, stream,
                       coords, packed,
                       p_i, p_j, p_coul, p_a12, p_b6, p_b10, n_pair,
                       q_i, q_j, q_coul, q_a12, q_b6, q_b10, n_pair14,
                       partials);

    hipLaunchKernelGGL(finalize_kernel, dim3(1), dim3(BLOCK), 0, stream,
                       partials, blocks, out);
}

// Round 6
// 264.825 us; speedup vs baseline: 1.0324x; 1.0324x over previous
//
#include <hip/hip_runtime.h>

// Inputs (setup_inputs order):
//  0: coords [100000*3] f32; 1-6: pair i/j/coul/a12/b6/b10 [8M];
//  7-12: pair14 i/j/coul/a12/b6/b10 [500K]
// Output: [4] f32 = [e_coul, e_lj, e_coul14, e_lj14]
//
// R5 post-mortem: 8-wide unroll broke stream coalescing (FETCH 106->122MB)
// and compiler serialized gathers to hold VGPR=48 (default 8-waves/EU budget).
// R6: two wave-coalesced chunks per iter (c and c+nthreads) -> 16 gathers in
// flight, streams stay 16B/lane contiguous; __launch_bounds__(256,4) gives a
// 128-VGPR budget so the compiler doesn't re-serialize.

#define BLOCK 256
#define GRID  2048

typedef int   intx4   __attribute__((ext_vector_type(4)));
typedef float floatx4 __attribute__((ext_vector_type(4)));

__global__ void pack_coords_kernel(const float* __restrict__ coords,
                                   float4* __restrict__ packed, int natom) {
    int i = blockIdx.x * blockDim.x + threadIdx.x;
    if (i < natom) {
        packed[i] = make_float4(coords[3 * i + 0], coords[3 * i + 1],
                                coords[3 * i + 2], 0.0f);
    }
}

__device__ __forceinline__ void pair_math(float4 ci, float4 cj, float coul,
                                          float a12, float b6, float b10,
                                          double& ec, double& ev) {
    float dx = ci.x - cj.x;
    float dy = ci.y - cj.y;
    float dz = ci.z - cj.z;
    float r2 = dx * dx + dy * dy + dz * dz;
    float inv_r2 = 1.0f / r2;
    float inv_r  = sqrtf(inv_r2);
    float inv_r6 = inv_r2 * inv_r2 * inv_r2;
    ec += (double)(coul * inv_r);
    ev += (double)(a12 * inv_r6 * inv_r6 - b6 * inv_r6
                 - b10 * inv_r6 * inv_r2 * inv_r2);
}

__device__ __forceinline__ void pair_term_packed(const float4* __restrict__ packed,
                                                 int i, int j, float coul, float a12,
                                                 float b6, float b10,
                                                 double& ec, double& ev) {
    pair_math(packed[i], packed[j], coul, a12, b6, b10, ec, ev);
}

__device__ __forceinline__ void pair_term_direct(const float* __restrict__ coords,
                                                 int i, int j, float coul, float a12,
                                                 float b6, float b10,
                                                 double& ec, double& ev) {
    int ia = i * 3, ja = j * 3;
    float4 ci = make_float4(coords[ia], coords[ia + 1], coords[ia + 2], 0.f);
    float4 cj = make_float4(coords[ja], coords[ja + 1], coords[ja + 2], 0.f);
    pair_math(ci, cj, coul, a12, b6, b10, ec, ev);
}

__device__ __forceinline__ void scan_list(const float* __restrict__ coords,
                                          const float4* __restrict__ packed,
                                          const int* __restrict__ ii,
                                          const int* __restrict__ jj,
                                          const float* __restrict__ coul,
                                          const float* __restrict__ a12,
                                          const float* __restrict__ b6,
                                          const float* __restrict__ b10,
                                          int n, int tid, int nthreads,
                                          double& ec, double& ev) {
    if (packed) {
        int n4 = n >> 2;
        int c  = tid;
        // Two wave-coalesced chunks per iteration: c and c+nthreads.
        for (; c + nthreads < n4; c += 2 * nthreads) {
            int cA = c, cB = c + nthreads;
            intx4 iA = __builtin_nontemporal_load(((const intx4*)ii) + cA);
            intx4 jA = __builtin_nontemporal_load(((const intx4*)jj) + cA);
            intx4 iB = __builtin_nontemporal_load(((const intx4*)ii) + cB);
            intx4 jB = __builtin_nontemporal_load(((const intx4*)jj) + cB);

            // 16 gathers issued before any consumption.
            float4 A0 = packed[iA.x], A1 = packed[iA.y],
                   A2 = packed[iA.z], A3 = packed[iA.w];
            float4 P0 = packed[jA.x], P1 = packed[jA.y],
                   P2 = packed[jA.z], P3 = packed[jA.w];
            float4 B0 = packed[iB.x], B1 = packed[iB.y],
                   B2 = packed[iB.z], B3 = packed[iB.w];
            float4 Q0 = packed[jB.x], Q1 = packed[jB.y],
                   Q2 = packed[jB.z], Q3 = packed[jB.w];

            floatx4 cA4 = __builtin_nontemporal_load(((const floatx4*)coul) + cA);
            floatx4 aA4 = __builtin_nontemporal_load(((const floatx4*)a12) + cA);
            floatx4 bA4 = __builtin_nontemporal_load(((const floatx4*)b6)  + cA);
            floatx4 hA4 = __builtin_nontemporal_load(((const floatx4*)b10) + cA);
            floatx4 cB4 = __builtin_nontemporal_load(((const floatx4*)coul) + cB);
            floatx4 aB4 = __builtin_nontemporal_load(((const floatx4*)a12) + cB);
            floatx4 bB4 = __builtin_nontemporal_load(((const floatx4*)b6)  + cB);
            floatx4 hB4 = __builtin_nontemporal_load(((const floatx4*)b10) + cB);

            pair_math(A0, P0, cA4.x, aA4.x, bA4.x, hA4.x, ec, ev);
            pair_math(A1, P1, cA4.y, aA4.y, bA4.y, hA4.y, ec, ev);
            pair_math(A2, P2, cA4.z, aA4.z, bA4.z, hA4.z, ec, ev);
            pair_math(A3, P3, cA4.w, aA4.w, bA4.w, hA4.w, ec, ev);
            pair_math(B0, Q0, cB4.x, aB4.x, bB4.x, hB4.x, ec, ev);
            pair_math(B1, Q1, cB4.y, aB4.y, bB4.y, hB4.y, ec, ev);
            pair_math(B2, Q2, cB4.z, aB4.z, bB4.z, hB4.z, ec, ev);
            pair_math(B3, Q3, cB4.w, aB4.w, bB4.w, hB4.w, ec, ev);
        }
        // Remainder chunk (<= 1 per thread).
        for (; c < n4; c += nthreads) {
            intx4 i4 = __builtin_nontemporal_load(((const intx4*)ii) + c);
            intx4 j4 = __builtin_nontemporal_load(((const intx4*)jj) + c);
            float4 A0 = packed[i4.x], A1 = packed[i4.y],
                   A2 = packed[i4.z], A3 = packed[i4.w];
            float4 P0 = packed[j4.x], P1 = packed[j4.y],
                   P2 = packed[j4.z], P3 = packed[j4.w];
            floatx4 c4 = __builtin_nontemporal_load(((const floatx4*)coul) + c);
            floatx4 a4 = __builtin_nontemporal_load(((const floatx4*)a12) + c);
            floatx4 b4 = __builtin_nontemporal_load(((const floatx4*)b6)  + c);
            floatx4 h4 = __builtin_nontemporal_load(((const floatx4*)b10) + c);
            pair_math(A0, P0, c4.x, a4.x, b4.x, h4.x, ec, ev);
            pair_math(A1, P1, c4.y, a4.y, b4.y, h4.y, ec, ev);
            pair_math(A2, P2, c4.z, a4.z, b4.z, h4.z, ec, ev);
            pair_math(A3, P3, c4.w, a4.w, b4.w, h4.w, ec, ev);
        }
        // Scalar tail (n % 4).
        int n4e = n4 << 2;
        for (int p = n4e + tid; p < n; p += nthreads) {
            pair_term_packed(packed, ii[p], jj[p], coul[p], a12[p], b6[p], b10[p], ec, ev);
        }
    } else {
        int n4 = n >> 2;
        for (int c = tid; c < n4; c += nthreads) {
            intx4   i4 = ((const intx4*)ii)[c];
            intx4   j4 = ((const intx4*)jj)[c];
            floatx4 c4 = ((const floatx4*)coul)[c];
            floatx4 a4 = ((const floatx4*)a12)[c];
            floatx4 b4 = ((const floatx4*)b6)[c];
            floatx4 h4 = ((const floatx4*)b10)[c];
            pair_term_direct(coords, i4.x, j4.x, c4.x, a4.x, b4.x, h4.x, ec, ev);
            pair_term_direct(coords, i4.y, j4.y, c4.y, a4.y, b4.y, h4.y, ec, ev);
            pair_term_direct(coords, i4.z, j4.z, c4.z, a4.z, b4.z, h4.z, ec, ev);
            pair_term_direct(coords, i4.w, j4.w, c4.w, a4.w, b4.w, h4.w, ec, ev);
        }
        for (int p = ((n >> 2) << 2) + tid; p < n; p += nthreads) {
            pair_term_direct(coords, ii[p], jj[p], coul[p], a12[p], b6[p], b10[p], ec, ev);
        }
    }
}

__global__ __launch_bounds__(BLOCK, 4) void fused_pair_kernel(
        const float* __restrict__ coords, const float4* __restrict__ packed,
        const int* __restrict__ p_i, const int* __restrict__ p_j,
        const float* __restrict__ p_coul, const float* __restrict__ p_a12,
        const float* __restrict__ p_b6, const float* __restrict__ p_b10, int n_pair,
        const int* __restrict__ q_i, const int* __restrict__ q_j,
        const float* __restrict__ q_coul, const float* __restrict__ q_a12,
        const float* __restrict__ q_b6, const float* __restrict__ q_b10, int n_pair14,
        double* __restrict__ partials) {
    double ec = 0.0, ev = 0.0, ec14 = 0.0, ev14 = 0.0;
    int tid = blockIdx.x * blockDim.x + threadIdx.x;
    int nthreads = gridDim.x * blockDim.x;

    scan_list(coords, packed, p_i, p_j, p_coul, p_a12, p_b6, p_b10, n_pair,
              tid, nthreads, ec, ev);
    scan_list(coords, packed, q_i, q_j, q_coul, q_a12, q_b6, q_b10, n_pair14,
              tid, nthreads, ec14, ev14);

    for (int off = 32; off > 0; off >>= 1) {
        ec   += __shfl_down(ec,   off, 64);
        ev   += __shfl_down(ev,   off, 64);
        ec14 += __shfl_down(ec14, off, 64);
        ev14 += __shfl_down(ev14, off, 64);
    }

    __shared__ double s[BLOCK / 64][4];
    int lane = threadIdx.x & 63;
    int wid  = threadIdx.x >> 6;
    if (lane == 0) { s[wid][0] = ec; s[wid][1] = ev; s[wid][2] = ec14; s[wid][3] = ev14; }
    __syncthreads();

    if (threadIdx.x == 0) {
        double t0 = 0, t1 = 0, t2 = 0, t3 = 0;
        for (int w = 0; w < BLOCK / 64; ++w) {
            t0 += s[w][0]; t1 += s[w][1]; t2 += s[w][2]; t3 += s[w][3];
        }
        double* row = partials + (size_t)blockIdx.x * 4;
        row[0] = t0; row[1] = t1; row[2] = t2; row[3] = t3;
    }
}

__global__ __launch_bounds__(BLOCK) void finalize_kernel(
        const double* __restrict__ partials, int nrows,
        float* __restrict__ out) {
    double acc0 = 0, acc1 = 0, acc2 = 0, acc3 = 0;
    for (int r = threadIdx.x; r < nrows; r += blockDim.x) {
        const double* row = partials + (size_t)r * 4;
        acc0 += row[0]; acc1 += row[1]; acc2 += row[2]; acc3 += row[3];
    }
    for (int off = 32; off > 0; off >>= 1) {
        acc0 += __shfl_down(acc0, off, 64);
        acc1 += __shfl_down(acc1, off, 64);
        acc2 += __shfl_down(acc2, off, 64);
        acc3 += __shfl_down(acc3, off, 64);
    }
    __shared__ double s[BLOCK / 64][4];
    int lane = threadIdx.x & 63;
    int wid  = threadIdx.x >> 6;
    if (lane == 0) { s[wid][0] = acc0; s[wid][1] = acc1; s[wid][2] = acc2; s[wid][3] = acc3; }
    __syncthreads();
    if (threadIdx.x == 0) {
        double t0 = 0, t1 = 0, t2 = 0, t3 = 0;
        for (int w = 0; w < BLOCK / 64; ++w) {
            t0 += s[w][0]; t1 += s[w][1]; t2 += s[w][2]; t3 += s[w][3];
        }
        out[0] = (float)t0; out[1] = (float)t1;
        out[2] = (float)t2; out[3] = (float)t3;
    }
}

extern "C" void kernel_launch(void* const* d_in, const int* in_sizes, int n_in,
                              void* d_out, int out_size, void* d_ws, size_t ws_size,
                              hipStream_t stream) {
    const float* coords = (const float*)d_in[0];
    int natom = in_sizes[0] / 3;

    const int*   p_i    = (const int*)d_in[1];
    const int*   p_j    = (const int*)d_in[2];
    const float* p_coul = (const float*)d_in[3];
    const float* p_a12  = (const float*)d_in[4];
    const float* p_b6   = (const float*)d_in[5];
    const float* p_b10  = (const float*)d_in[6];
    int n_pair = in_sizes[1];

    const int*   q_i    = (const int*)d_in[7];
    const int*   q_j    = (const int*)d_in[8];
    const float* q_coul = (const float*)d_in[9];
    const float* q_a12  = (const float*)d_in[10];
    const float* q_b6   = (const float*)d_in[11];
    const float* q_b10  = (const float*)d_in[12];
    int n_pair14 = in_sizes[7];

    float* out = (float*)d_out;

    // d_ws layout: [packed coords: natom*16B] [partials: GRID*32B]
    size_t packed_bytes = (size_t)natom * sizeof(float4);
    size_t need = packed_bytes + (size_t)GRID * 4 * sizeof(double);

    float4* packed   = nullptr;
    double* partials = (double*)d_ws;
    int blocks = GRID;

    if (ws_size >= need) {
        packed   = (float4*)d_ws;
        partials = (double*)((char*)d_ws + packed_bytes);
        hipLaunchKernelGGL(pack_coords_kernel,
                           dim3((natom + BLOCK - 1) / BLOCK), dim3(BLOCK), 0, stream,
                           coords, packed, natom);
    } else {
        size_t max_blocks = ws_size / (4 * sizeof(double));
        if ((size_t)blocks > max_blocks) blocks = (int)max_blocks;
        if (blocks < 1) blocks = 1;
    }

    hipLaunchKernelGGL(fused_pair_kernel, dim3(blocks), dim3(BLOCK), 0, stream,
                       coords, packed,
                       p_i, p_j, p_coul, p_a12, p_b6, p_b10, n_pair,
                       q_i, q_j, q_coul, q_a12, q_b6, q_b10, n_pair14,
                       partials);

    hipLaunchKernelGGL(finalize_kernel, dim3(1), dim3(BLOCK), 0, stream,
                       partials, blocks, out);
}